// Round 1
// baseline (4126.994 us; speedup 1.0000x reference)
//
#include <hip/hip_runtime.h>
#include <math.h>

typedef unsigned int uint32;
typedef unsigned short ushort_t;

typedef __attribute__((ext_vector_type(8))) short short8;
typedef __attribute__((ext_vector_type(4))) float floatx4;

#define SEQL 2048
#define DIMC 768
#define NHEAD 12
#define HDIM 64
#define HIDV 2042
#define HIDP 2048
#define NVOCAB 32000
#define QSZ (DIMC*DIMC)      // 589824
#define PSZ (HIDP*DIMC)      // 1572864
#define W2SRC (DIMC*HIDV)    // 1568256

__device__ __forceinline__ ushort_t f2bf(float f) {
    uint32 u = __float_as_uint(f);
    u += 0x7FFFu + ((u >> 16) & 1u);   // round-to-nearest-even
    return (ushort_t)(u >> 16);
}
__device__ __forceinline__ float bf2f(ushort_t h) {
    return __uint_as_float(((uint32)h) << 16);
}

// ---------------- GEMM: C[M,N] (=|+=) A[M,K] * B[N,K]^T, bf16 inputs -------
// OUTMODE: 0 = store f32, 1 = store bf16, 2 = accumulate into f32 (residual)
template<int WTM, int WTN, int WVM, int WVN, int OUTMODE>
__global__ __launch_bounds__(WVM*WVN*64)
void gemm_kernel(const ushort_t* __restrict__ A, int lda,
                 const ushort_t* __restrict__ B, int ldb,
                 void* __restrict__ C, int ldc, int K)
{
    const int wid  = threadIdx.x >> 6;
    const int lane = threadIdx.x & 63;
    const int wm = wid % WVM, wn = wid / WVM;
    const int r = lane & 15, quad = lane >> 4;
    const int m0 = blockIdx.x * (WVM*WTM*16) + wm * (WTM*16);
    const int n0 = blockIdx.y * (WVN*WTN*16) + wn * (WTN*16);

    floatx4 acc[WTM][WTN];
#pragma unroll
    for (int i = 0; i < WTM; ++i)
#pragma unroll
        for (int j = 0; j < WTN; ++j)
            acc[i][j] = (floatx4){0.f, 0.f, 0.f, 0.f};

    const ushort_t* Ap = A + (size_t)(m0 + r) * lda + quad * 8;
    const ushort_t* Bp = B + (size_t)(n0 + r) * ldb + quad * 8;
    for (int k0 = 0; k0 < K; k0 += 32) {
        short8 af[WTM], bfr[WTN];
#pragma unroll
        for (int i = 0; i < WTM; ++i) af[i] = *(const short8*)(Ap + (size_t)i * 16 * lda);
#pragma unroll
        for (int j = 0; j < WTN; ++j) bfr[j] = *(const short8*)(Bp + (size_t)j * 16 * ldb);
#pragma unroll
        for (int i = 0; i < WTM; ++i)
#pragma unroll
            for (int j = 0; j < WTN; ++j)
                acc[i][j] = __builtin_amdgcn_mfma_f32_16x16x32_bf16(af[i], bfr[j], acc[i][j], 0, 0, 0);
        Ap += 32; Bp += 32;
    }

#pragma unroll
    for (int i = 0; i < WTM; ++i) {
#pragma unroll
        for (int j = 0; j < WTN; ++j) {
#pragma unroll
            for (int t = 0; t < 4; ++t) {
                const int row = m0 + i * 16 + quad * 4 + t;   // C/D: row=quad*4+reg
                const int col = n0 + j * 16 + r;              //      col=lane&15
                const size_t off = (size_t)row * ldc + col;
                const float v = acc[i][j][t];
                if (OUTMODE == 2)      ((float*)C)[off] += v;
                else if (OUTMODE == 1) ((ushort_t*)C)[off] = f2bf(v);
                else                   ((float*)C)[off] = v;
            }
        }
    }
}

// ---------------- RMSNorm: fp32 in -> bf16 out, one wave per row -----------
__global__ __launch_bounds__(256)
void rmsnorm_kernel(const float* __restrict__ x, const float* __restrict__ g,
                    ushort_t* __restrict__ out)
{
    const int w = threadIdx.x >> 6, lane = threadIdx.x & 63;
    const int row = blockIdx.x * 4 + w;
    const float* xr = x + (size_t)row * DIMC;
    float4 a = *(const float4*)(xr + lane * 4);
    float4 b = *(const float4*)(xr + 256 + lane * 4);
    float4 c = *(const float4*)(xr + 512 + lane * 4);
    float ss = a.x*a.x + a.y*a.y + a.z*a.z + a.w*a.w
             + b.x*b.x + b.y*b.y + b.z*b.z + b.w*b.w
             + c.x*c.x + c.y*c.y + c.z*c.z + c.w*c.w;
#pragma unroll
    for (int off = 32; off > 0; off >>= 1) ss += __shfl_xor(ss, off, 64);
    const float inv = rsqrtf(ss * (1.0f / DIMC) + 1e-6f);
    float4 ga = *(const float4*)(g + lane * 4);
    float4 gb = *(const float4*)(g + 256 + lane * 4);
    float4 gc = *(const float4*)(g + 512 + lane * 4);
    ushort_t* orow = out + (size_t)row * DIMC;
    *(ushort4*)(orow + lane * 4)       = make_ushort4(f2bf(a.x*inv*ga.x), f2bf(a.y*inv*ga.y), f2bf(a.z*inv*ga.z), f2bf(a.w*inv*ga.w));
    *(ushort4*)(orow + 256 + lane * 4) = make_ushort4(f2bf(b.x*inv*gb.x), f2bf(b.y*inv*gb.y), f2bf(b.z*inv*gb.z), f2bf(b.w*inv*gb.w));
    *(ushort4*)(orow + 512 + lane * 4) = make_ushort4(f2bf(c.x*inv*gc.x), f2bf(c.y*inv*gc.y), f2bf(c.z*inv*gc.z), f2bf(c.w*inv*gc.w));
}

// ---------------- RoPE in-place on bf16 [S,12,64] --------------------------
__global__ __launch_bounds__(256)
void rope_kernel(ushort_t* __restrict__ x)
{
    const int idx = blockIdx.x * 256 + threadIdx.x;   // SEQL*NHEAD*32
    const int j = idx & 31;
    const int h = (idx >> 5) % NHEAD;
    const int s = idx / (32 * NHEAD);
    // freq = 10000^{-2j/64} = exp(-(ln(10000)/32) * j)
    const float freq = expf(-0.28782313662425574f * (float)j);
    const float ang = (float)s * freq;
    const float sn = sinf(ang), cs = cosf(ang);
    ushort_t* p = x + (size_t)s * DIMC + h * HDIM + 2 * j;
    const float a = bf2f(p[0]), b = bf2f(p[1]);
    p[0] = f2bf(a * cs - b * sn);
    p[1] = f2bf(a * sn + b * cs);
}

// ---------------- Attention: one wave per (head, q), online softmax --------
__global__ __launch_bounds__(256)
void attn_kernel(const ushort_t* __restrict__ q, const ushort_t* __restrict__ k,
                 const ushort_t* __restrict__ v, ushort_t* __restrict__ o)
{
    __shared__ float qlds[4][64];
    __shared__ float plds[4][64];
    const int w = threadIdx.x >> 6, lane = threadIdx.x & 63;
    const int h = blockIdx.y;
    const int qi = blockIdx.x * 4 + w;
    const int hb = h * HDIM;
    qlds[w][lane] = bf2f(q[(size_t)qi * DIMC + hb + lane]) * 0.125f;  // fold 1/sqrt(64)
    float m = -INFINITY, l = 0.f, oacc = 0.f;
    for (int k0 = 0; k0 <= qi; k0 += 64) {
        const int kk = k0 + lane;                 // k0<=1984 so kk<=2047: in-bounds
        const ushort_t* krow = k + (size_t)kk * DIMC + hb;
        float s = 0.f;
#pragma unroll
        for (int d = 0; d < 64; d += 8) {
            short8 kv = *(const short8*)(krow + d);
            s += qlds[w][d+0] * bf2f((ushort_t)kv[0]);
            s += qlds[w][d+1] * bf2f((ushort_t)kv[1]);
            s += qlds[w][d+2] * bf2f((ushort_t)kv[2]);
            s += qlds[w][d+3] * bf2f((ushort_t)kv[3]);
            s += qlds[w][d+4] * bf2f((ushort_t)kv[4]);
            s += qlds[w][d+5] * bf2f((ushort_t)kv[5]);
            s += qlds[w][d+6] * bf2f((ushort_t)kv[6]);
            s += qlds[w][d+7] * bf2f((ushort_t)kv[7]);
        }
        if (kk > qi) s = -INFINITY;               // causal mask
        float mc = s;
#pragma unroll
        for (int off = 32; off > 0; off >>= 1) mc = fmaxf(mc, __shfl_xor(mc, off, 64));
        const float mnew = fmaxf(m, mc);
        const float p = __expf(s - mnew);
        const float alpha = __expf(m - mnew);
        float ps = p;
#pragma unroll
        for (int off = 32; off > 0; off >>= 1) ps += __shfl_xor(ps, off, 64);
        l = l * alpha + ps;
        plds[w][lane] = p;
        oacc *= alpha;
        const ushort_t* vcol = v + (size_t)k0 * DIMC + hb + lane;  // lane = dim
#pragma unroll 16
        for (int j = 0; j < 64; ++j)
            oacc = fmaf(plds[w][j], bf2f(vcol[(size_t)j * DIMC]), oacc);
        m = mnew;
    }
    o[(size_t)qi * DIMC + hb + lane] = f2bf(oacc / l);
}

// ---------------- SiLU(y1) * y3 -> bf16 (padded cols are already 0) --------
__global__ __launch_bounds__(256)
void silu_mul_kernel(const float* __restrict__ y1, const float* __restrict__ y3,
                     ushort_t* __restrict__ hs)
{
    const size_t idx = (size_t)(blockIdx.x * 256 + threadIdx.x);
    float4 a = *(const float4*)(y1 + idx * 4);
    float4 b = *(const float4*)(y3 + idx * 4);
    float4 r;
    r.x = a.x / (1.f + __expf(-a.x)) * b.x;
    r.y = a.y / (1.f + __expf(-a.y)) * b.y;
    r.z = a.z / (1.f + __expf(-a.z)) * b.z;
    r.w = a.w / (1.f + __expf(-a.w)) * b.w;
    *(ushort4*)(hs + idx * 4) = make_ushort4(f2bf(r.x), f2bf(r.y), f2bf(r.z), f2bf(r.w));
}

// ---------------- Embedding gather (fp32) ----------------------------------
__global__ __launch_bounds__(256)
void embed_kernel(const int* __restrict__ tok, const float* __restrict__ emb,
                  float* __restrict__ h)
{
    const int idx = blockIdx.x * 256 + threadIdx.x;    // SEQL*192
    const int s = idx / 192, c = (idx % 192) * 4;
    const int t = tok[s];
    *(float4*)(h + (size_t)s * DIMC + c) = *(const float4*)(emb + (size_t)t * DIMC + c);
}

// ---------------- Per-layer weight conversion fp32 -> bf16 (with padding) --
__global__ __launch_bounds__(256)
void conv_layer_kernel(const float* __restrict__ wq, const float* __restrict__ wk,
                       const float* __restrict__ wv, const float* __restrict__ wo,
                       const float* __restrict__ w1, const float* __restrict__ w2,
                       const float* __restrict__ w3,
                       ushort_t* __restrict__ wqb, ushort_t* __restrict__ wkb,
                       ushort_t* __restrict__ wvb, ushort_t* __restrict__ wob,
                       ushort_t* __restrict__ w1p, ushort_t* __restrict__ w3p,
                       ushort_t* __restrict__ w2p)
{
    int idx = blockIdx.x * 256 + threadIdx.x;
    if (idx < 4 * QSZ) {
        const int m = idx / QSZ, i = idx - m * QSZ;
        const float* s = (m == 0) ? wq : (m == 1) ? wk : (m == 2) ? wv : wo;
        ushort_t*   d = (m == 0) ? wqb : (m == 1) ? wkb : (m == 2) ? wvb : wob;
        d[i] = f2bf(s[i]);
        return;
    }
    idx -= 4 * QSZ;
    if (idx < PSZ) {   // w1 padded: [2048][768], rows >= 2042 zero
        const int n = idx / DIMC, kk = idx - n * DIMC;
        w1p[idx] = (n < HIDV) ? f2bf(w1[(size_t)n * DIMC + kk]) : (ushort_t)0;
        return;
    }
    idx -= PSZ;
    if (idx < PSZ) {
        const int n = idx / DIMC, kk = idx - n * DIMC;
        w3p[idx] = (n < HIDV) ? f2bf(w3[(size_t)n * DIMC + kk]) : (ushort_t)0;
        return;
    }
    idx -= PSZ;
    if (idx < PSZ) {   // w2 padded: [768][2048], cols >= 2042 zero
        const int n = idx >> 11, kk = idx & 2047;
        w2p[idx] = (kk < HIDV) ? f2bf(w2[(size_t)n * HIDV + kk]) : (ushort_t)0;
        return;
    }
}

// ---------------- out_w conversion fp32 -> bf16 ----------------------------
__global__ __launch_bounds__(256)
void conv_outw_kernel(const float* __restrict__ src, ushort_t* __restrict__ dst)
{
    const size_t idx = (size_t)(blockIdx.x * 256 + threadIdx.x);
    float4 a = *(const float4*)(src + idx * 4);
    *(ushort4*)(dst + idx * 4) = make_ushort4(f2bf(a.x), f2bf(a.y), f2bf(a.z), f2bf(a.w));
}

extern "C" void kernel_launch(void* const* d_in, const int* in_sizes, int n_in,
                              void* d_out, int out_size, void* d_ws, size_t ws_size,
                              hipStream_t stream)
{
    const int*   tok  = (const int*)d_in[0];
    const float* emb  = (const float*)d_in[1];
    const float* wq   = (const float*)d_in[2];
    const float* wk   = (const float*)d_in[3];
    const float* wv   = (const float*)d_in[4];
    const float* wo   = (const float*)d_in[5];
    const float* w1   = (const float*)d_in[6];
    const float* w2   = (const float*)d_in[7];
    const float* w3   = (const float*)d_in[8];
    const float* anw  = (const float*)d_in[9];
    const float* fnw  = (const float*)d_in[10];
    const float* nw   = (const float*)d_in[11];
    const float* outw = (const float*)d_in[12];
    float* out = (float*)d_out;
    (void)in_sizes; (void)n_in; (void)out_size; (void)ws_size;

    char* p = (char*)d_ws;
    auto alloc = [&](size_t bytes) { char* r = p; p += (bytes + 255) & ~(size_t)255; return r; };
    float*    H   = (float*)   alloc((size_t)SEQL * DIMC * 4);
    ushort_t* XN  = (ushort_t*)alloc((size_t)SEQL * DIMC * 2);
    ushort_t* YN  = (ushort_t*)alloc((size_t)SEQL * DIMC * 2);
    ushort_t* WQB = (ushort_t*)alloc((size_t)QSZ * 2);
    ushort_t* WKB = (ushort_t*)alloc((size_t)QSZ * 2);
    ushort_t* WVB = (ushort_t*)alloc((size_t)QSZ * 2);
    ushort_t* WOB = (ushort_t*)alloc((size_t)QSZ * 2);
    ushort_t* W1P = (ushort_t*)alloc((size_t)PSZ * 2);
    ushort_t* W3P = (ushort_t*)alloc((size_t)PSZ * 2);
    ushort_t* W2P = (ushort_t*)alloc((size_t)PSZ * 2);
    // region below is reused late as bf16 out_w (54.5 MB >= 49.15 MB)
    ushort_t* QB  = (ushort_t*)alloc((size_t)SEQL * DIMC * 2);
    ushort_t* KB  = (ushort_t*)alloc((size_t)SEQL * DIMC * 2);
    ushort_t* VB  = (ushort_t*)alloc((size_t)SEQL * DIMC * 2);
    ushort_t* AO  = (ushort_t*)alloc((size_t)SEQL * DIMC * 2);
    float*    Y1  = (float*)   alloc((size_t)SEQL * HIDP * 4);
    float*    Y3  = (float*)   alloc((size_t)SEQL * HIDP * 4);
    ushort_t* HS  = (ushort_t*)alloc((size_t)SEQL * HIDP * 2);
    ushort_t* OUTWB = QB;  // aliased, used only after last layer

    embed_kernel<<<1536, 256, 0, stream>>>(tok, emb, H);

    for (int l = 0; l < 4; ++l) {
        conv_layer_kernel<<<27648, 256, 0, stream>>>(
            wq + (size_t)l * QSZ, wk + (size_t)l * QSZ, wv + (size_t)l * QSZ, wo + (size_t)l * QSZ,
            w1 + (size_t)l * W2SRC, w2 + (size_t)l * W2SRC, w3 + (size_t)l * W2SRC,
            WQB, WKB, WVB, WOB, W1P, W3P, W2P);

        rmsnorm_kernel<<<512, 256, 0, stream>>>(H, anw + (size_t)l * DIMC, XN);

        // QKV projections (bf16 out): M=2048 N=768 K=768, 64x64 tiles
        gemm_kernel<2,2,2,2,1><<<dim3(32,12), 256, 0, stream>>>(XN, DIMC, WQB, DIMC, QB, DIMC, DIMC);
        gemm_kernel<2,2,2,2,1><<<dim3(32,12), 256, 0, stream>>>(XN, DIMC, WKB, DIMC, KB, DIMC, DIMC);
        gemm_kernel<2,2,2,2,1><<<dim3(32,12), 256, 0, stream>>>(XN, DIMC, WVB, DIMC, VB, DIMC, DIMC);

        rope_kernel<<<3072, 256, 0, stream>>>(QB);
        rope_kernel<<<3072, 256, 0, stream>>>(KB);

        attn_kernel<<<dim3(512, NHEAD), 256, 0, stream>>>(QB, KB, VB, AO);

        // o @ wo^T, accumulate into H (residual)
        gemm_kernel<2,2,2,2,2><<<dim3(32,12), 256, 0, stream>>>(AO, DIMC, WOB, DIMC, H, DIMC, DIMC);

        rmsnorm_kernel<<<512, 256, 0, stream>>>(H, fnw + (size_t)l * DIMC, YN);

        // FFN up: M=2048 N=2048(pad) K=768, 128x128 tiles
        gemm_kernel<4,4,2,2,0><<<dim3(16,16), 256, 0, stream>>>(YN, DIMC, W1P, DIMC, Y1, HIDP, DIMC);
        gemm_kernel<4,4,2,2,0><<<dim3(16,16), 256, 0, stream>>>(YN, DIMC, W3P, DIMC, Y3, HIDP, DIMC);

        silu_mul_kernel<<<4096, 256, 0, stream>>>(Y1, Y3, HS);

        // FFN down: M=2048 N=768 K=2048(pad), accumulate into H
        gemm_kernel<2,2,2,2,2><<<dim3(32,12), 256, 0, stream>>>(HS, HIDP, W2P, HIDP, H, DIMC, HIDP);
    }

    rmsnorm_kernel<<<512, 256, 0, stream>>>(H, nw, XN);
    conv_outw_kernel<<<24000, 256, 0, stream>>>(outw, OUTWB);
    // logits: M=2048 N=32000 K=768, 128x128 tiles, f32 out
    gemm_kernel<4,4,2,2,0><<<dim3(16,250), 256, 0, stream>>>(XN, DIMC, OUTWB, DIMC, out, NVOCAB, DIMC);
}

// Round 2
// 2412.410 us; speedup vs baseline: 1.7107x; 1.7107x over previous
//
#include <hip/hip_runtime.h>
#include <math.h>

typedef unsigned int uint32;
typedef unsigned short ushort_t;

typedef __attribute__((ext_vector_type(8))) short short8;
typedef __attribute__((ext_vector_type(4))) float floatx4;

#define SEQL 2048
#define DIMC 768
#define NHEAD 12
#define HDIM 64
#define HIDV 2042
#define HIDP 2048
#define NVOCAB 32000
#define QSZ (DIMC*DIMC)      // 589824
#define PSZ (HIDP*DIMC)      // 1572864
#define W2SRC (DIMC*HIDV)    // 1568256

__device__ __forceinline__ ushort_t f2bf(float f) {
    uint32 u = __float_as_uint(f);
    u += 0x7FFFu + ((u >> 16) & 1u);   // round-to-nearest-even
    return (ushort_t)(u >> 16);
}
__device__ __forceinline__ float bf2f(ushort_t h) {
    return __uint_as_float(((uint32)h) << 16);
}

union Frag { short8 s8; uint32 u[4]; ushort_t us[8]; };

// ---------------- GEMM: C[M,N] (=|+=) A[M,K] * B[N,K]^T, bf16 inputs -------
// OUTMODE: 0 = store f32, 1 = store bf16, 2 = accumulate into f32 (residual)
template<int WTM, int WTN, int WVM, int WVN, int OUTMODE>
__global__ __launch_bounds__(WVM*WVN*64)
void gemm_kernel(const ushort_t* __restrict__ A, int lda,
                 const ushort_t* __restrict__ B, int ldb,
                 void* __restrict__ C, int ldc, int K)
{
    const int wid  = threadIdx.x >> 6;
    const int lane = threadIdx.x & 63;
    const int wm = wid % WVM, wn = wid / WVM;
    const int r = lane & 15, quad = lane >> 4;
    const int m0 = blockIdx.x * (WVM*WTM*16) + wm * (WTM*16);
    const int n0 = blockIdx.y * (WVN*WTN*16) + wn * (WTN*16);

    floatx4 acc[WTM][WTN];
#pragma unroll
    for (int i = 0; i < WTM; ++i)
#pragma unroll
        for (int j = 0; j < WTN; ++j)
            acc[i][j] = (floatx4){0.f, 0.f, 0.f, 0.f};

    const ushort_t* Ap = A + (size_t)(m0 + r) * lda + quad * 8;
    const ushort_t* Bp = B + (size_t)(n0 + r) * ldb + quad * 8;
    for (int k0 = 0; k0 < K; k0 += 32) {
        short8 af[WTM], bfr[WTN];
#pragma unroll
        for (int i = 0; i < WTM; ++i) af[i] = *(const short8*)(Ap + (size_t)i * 16 * lda);
#pragma unroll
        for (int j = 0; j < WTN; ++j) bfr[j] = *(const short8*)(Bp + (size_t)j * 16 * ldb);
#pragma unroll
        for (int i = 0; i < WTM; ++i)
#pragma unroll
            for (int j = 0; j < WTN; ++j)
                acc[i][j] = __builtin_amdgcn_mfma_f32_16x16x32_bf16(af[i], bfr[j], acc[i][j], 0, 0, 0);
        Ap += 32; Bp += 32;
    }

#pragma unroll
    for (int i = 0; i < WTM; ++i) {
#pragma unroll
        for (int j = 0; j < WTN; ++j) {
#pragma unroll
            for (int t = 0; t < 4; ++t) {
                const int row = m0 + i * 16 + quad * 4 + t;   // C/D: row=quad*4+reg
                const int col = n0 + j * 16 + r;              //      col=lane&15
                const size_t off = (size_t)row * ldc + col;
                const float v = acc[i][j][t];
                if (OUTMODE == 2)      ((float*)C)[off] += v;
                else if (OUTMODE == 1) ((ushort_t*)C)[off] = f2bf(v);
                else                   ((float*)C)[off] = v;
            }
        }
    }
}

// ---------------- RMSNorm: fp32 in -> bf16 out, one wave per row -----------
__global__ __launch_bounds__(256)
void rmsnorm_kernel(const float* __restrict__ x, const float* __restrict__ g,
                    ushort_t* __restrict__ out)
{
    const int w = threadIdx.x >> 6, lane = threadIdx.x & 63;
    const int row = blockIdx.x * 4 + w;
    const float* xr = x + (size_t)row * DIMC;
    float4 a = *(const float4*)(xr + lane * 4);
    float4 b = *(const float4*)(xr + 256 + lane * 4);
    float4 c = *(const float4*)(xr + 512 + lane * 4);
    float ss = a.x*a.x + a.y*a.y + a.z*a.z + a.w*a.w
             + b.x*b.x + b.y*b.y + b.z*b.z + b.w*b.w
             + c.x*c.x + c.y*c.y + c.z*c.z + c.w*c.w;
#pragma unroll
    for (int off = 32; off > 0; off >>= 1) ss += __shfl_xor(ss, off, 64);
    const float inv = rsqrtf(ss * (1.0f / DIMC) + 1e-6f);
    float4 ga = *(const float4*)(g + lane * 4);
    float4 gb = *(const float4*)(g + 256 + lane * 4);
    float4 gc = *(const float4*)(g + 512 + lane * 4);
    ushort_t* orow = out + (size_t)row * DIMC;
    *(ushort4*)(orow + lane * 4)       = make_ushort4(f2bf(a.x*inv*ga.x), f2bf(a.y*inv*ga.y), f2bf(a.z*inv*ga.z), f2bf(a.w*inv*ga.w));
    *(ushort4*)(orow + 256 + lane * 4) = make_ushort4(f2bf(b.x*inv*gb.x), f2bf(b.y*inv*gb.y), f2bf(b.z*inv*gb.z), f2bf(b.w*inv*gb.w));
    *(ushort4*)(orow + 512 + lane * 4) = make_ushort4(f2bf(c.x*inv*gc.x), f2bf(c.y*inv*gc.y), f2bf(c.z*inv*gc.z), f2bf(c.w*inv*gc.w));
}

// ---------------- RoPE in-place on bf16 [S,12,64] --------------------------
__global__ __launch_bounds__(256)
void rope_kernel(ushort_t* __restrict__ x)
{
    const int idx = blockIdx.x * 256 + threadIdx.x;   // SEQL*NHEAD*32
    const int j = idx & 31;
    const int h = (idx >> 5) % NHEAD;
    const int s = idx / (32 * NHEAD);
    const float freq = expf(-0.28782313662425574f * (float)j);
    const float ang = (float)s * freq;
    const float sn = sinf(ang), cs = cosf(ang);
    ushort_t* p = x + (size_t)s * DIMC + h * HDIM + 2 * j;
    const float a = bf2f(p[0]), b = bf2f(p[1]);
    p[0] = f2bf(a * cs - b * sn);
    p[1] = f2bf(a * sn + b * cs);
}

// ---------------- MFMA flash attention (S^T trick, no LDS, no barriers) ----
// Per wave: 16 q rows. S^T = K·Q^T via mfma -> lane holds scores for fixed
// q=qb+(lane&15), keys kc+16c+4*quad+t. Online softmax state per-lane.
// P's C-layout == B-operand layout under key permutation
// pi(kappa=8*quad+j) = 16*(j>>2) + 4*quad + (j&3), absorbed into V^T reads.
// O^T = V^T·P accumulated in C-layout; alpha rescale is in-lane.
// V^T [DIMC][SEQL] comes free from the swapped V-projection GEMM.
__global__ __launch_bounds__(256)
void attn_mfma_kernel(const ushort_t* __restrict__ Q, const ushort_t* __restrict__ K,
                      const ushort_t* __restrict__ VT, ushort_t* __restrict__ O)
{
    const int w = threadIdx.x >> 6, lane = threadIdx.x & 63;
    const int r = lane & 15, quad = lane >> 4;
    const int hb = blockIdx.y * HDIM;
    const int qb = blockIdx.x * 64 + w * 16;

    // Q fragments (B operand): B[n=r][k=quad*8+j] = Q[qb+r][hb+fi*32+quad*8+j] * 1/8
    Frag bq[2];
    {
        const ushort_t* qp = Q + (size_t)(qb + r) * DIMC + hb + quad * 8;
#pragma unroll
        for (int fi = 0; fi < 2; ++fi) {
            Frag t; t.s8 = *(const short8*)(qp + fi * 32);
#pragma unroll
            for (int e = 0; e < 8; ++e) t.us[e] = f2bf(bf2f(t.us[e]) * 0.125f);
            bq[fi] = t;
        }
    }

    floatx4 o[4];
#pragma unroll
    for (int dg = 0; dg < 4; ++dg) o[dg] = (floatx4){0.f, 0.f, 0.f, 0.f};
    float m = -INFINITY, l = 0.f;

    const int kend = qb + 16;
    for (int kc = 0; kc < kend; kc += 32) {
        // K fragments (A operand): A[m=r][k=quad*8+j] = K[kc+16c+r][hb+fi*32+quad*8+j]
        const ushort_t* kp = K + (size_t)(kc + r) * DIMC + hb + quad * 8;
        const short8 ak00 = *(const short8*)(kp);
        const short8 ak01 = *(const short8*)(kp + 32);
        const short8 ak10 = *(const short8*)(kp + (size_t)16 * DIMC);
        const short8 ak11 = *(const short8*)(kp + (size_t)16 * DIMC + 32);

        floatx4 st0 = (floatx4){0.f, 0.f, 0.f, 0.f};
        floatx4 st1 = (floatx4){0.f, 0.f, 0.f, 0.f};
        st0 = __builtin_amdgcn_mfma_f32_16x16x32_bf16(ak00, bq[0].s8, st0, 0, 0, 0);
        st0 = __builtin_amdgcn_mfma_f32_16x16x32_bf16(ak01, bq[1].s8, st0, 0, 0, 0);
        st1 = __builtin_amdgcn_mfma_f32_16x16x32_bf16(ak10, bq[0].s8, st1, 0, 0, 0);
        st1 = __builtin_amdgcn_mfma_f32_16x16x32_bf16(ak11, bq[1].s8, st1, 0, 0, 0);

        // causal mask — only the boundary chunk needs it
        if (kc + 31 > qb) {
            const int q = qb + r;
#pragma unroll
            for (int t = 0; t < 4; ++t) {
                if (kc + quad * 4 + t > q)      st0[t] = -INFINITY;
                if (kc + 16 + quad * 4 + t > q) st1[t] = -INFINITY;
            }
        }

        // online softmax (state per lane; q = qb + r, replicated across quads)
        float vm = fmaxf(fmaxf(fmaxf(st0[0], st0[1]), fmaxf(st0[2], st0[3])),
                         fmaxf(fmaxf(st1[0], st1[1]), fmaxf(st1[2], st1[3])));
        vm = fmaxf(vm, __shfl_xor(vm, 16, 64));
        vm = fmaxf(vm, __shfl_xor(vm, 32, 64));
        const float mnew = fmaxf(m, vm);
        const float alpha = __expf(m - mnew);
        const float p0 = __expf(st0[0] - mnew), p1 = __expf(st0[1] - mnew);
        const float p2 = __expf(st0[2] - mnew), p3 = __expf(st0[3] - mnew);
        const float p4 = __expf(st1[0] - mnew), p5 = __expf(st1[1] - mnew);
        const float p6 = __expf(st1[2] - mnew), p7 = __expf(st1[3] - mnew);
        float ps = ((p0 + p1) + (p2 + p3)) + ((p4 + p5) + (p6 + p7));
        ps += __shfl_xor(ps, 16, 64);
        ps += __shfl_xor(ps, 32, 64);
        l = l * alpha + ps;
        m = mnew;

        // P fragment (B operand) — identity in-lane under pi
        Frag ap;
        ap.u[0] = (uint32)f2bf(p0) | ((uint32)f2bf(p1) << 16);
        ap.u[1] = (uint32)f2bf(p2) | ((uint32)f2bf(p3) << 16);
        ap.u[2] = (uint32)f2bf(p4) | ((uint32)f2bf(p5) << 16);
        ap.u[3] = (uint32)f2bf(p6) | ((uint32)f2bf(p7) << 16);

        // O^T rescale + PV: o[dg] = mfma(A=V^T frag, B=P frag, o[dg]*alpha)
#pragma unroll
        for (int dg = 0; dg < 4; ++dg) {
            const ushort_t* vp = VT + (size_t)(hb + dg * 16 + r) * SEQL + kc + quad * 4;
            Frag av;
            const uint2 v0 = *(const uint2*)(vp);        // keys kc+4*quad+{0..3}
            const uint2 v1 = *(const uint2*)(vp + 16);   // keys kc+16+4*quad+{0..3}
            av.u[0] = v0.x; av.u[1] = v0.y; av.u[2] = v1.x; av.u[3] = v1.y;
            o[dg] *= alpha;
            o[dg] = __builtin_amdgcn_mfma_f32_16x16x32_bf16(av.s8, ap.s8, o[dg], 0, 0, 0);
        }
    }

    // write O: lane holds O^T[d=dg*16+quad*4+t][q=qb+r]
    const float inv = 1.0f / l;
    ushort_t* op = O + (size_t)(qb + r) * DIMC + hb + quad * 4;
#pragma unroll
    for (int dg = 0; dg < 4; ++dg) {
        uint2 pkd;
        pkd.x = (uint32)f2bf(o[dg][0] * inv) | ((uint32)f2bf(o[dg][1] * inv) << 16);
        pkd.y = (uint32)f2bf(o[dg][2] * inv) | ((uint32)f2bf(o[dg][3] * inv) << 16);
        *(uint2*)(op + dg * 16) = pkd;
    }
}

// ---------------- SiLU(y1) * y3 -> bf16 (padded cols are already 0) --------
__global__ __launch_bounds__(256)
void silu_mul_kernel(const float* __restrict__ y1, const float* __restrict__ y3,
                     ushort_t* __restrict__ hs)
{
    const size_t idx = (size_t)(blockIdx.x * 256 + threadIdx.x);
    float4 a = *(const float4*)(y1 + idx * 4);
    float4 b = *(const float4*)(y3 + idx * 4);
    float4 r;
    r.x = a.x / (1.f + __expf(-a.x)) * b.x;
    r.y = a.y / (1.f + __expf(-a.y)) * b.y;
    r.z = a.z / (1.f + __expf(-a.z)) * b.z;
    r.w = a.w / (1.f + __expf(-a.w)) * b.w;
    *(ushort4*)(hs + idx * 4) = make_ushort4(f2bf(r.x), f2bf(r.y), f2bf(r.z), f2bf(r.w));
}

// ---------------- Embedding gather (fp32) ----------------------------------
__global__ __launch_bounds__(256)
void embed_kernel(const int* __restrict__ tok, const float* __restrict__ emb,
                  float* __restrict__ h)
{
    const int idx = blockIdx.x * 256 + threadIdx.x;    // SEQL*192
    const int s = idx / 192, c = (idx % 192) * 4;
    const int t = tok[s];
    *(float4*)(h + (size_t)s * DIMC + c) = *(const float4*)(emb + (size_t)t * DIMC + c);
}

// ---------------- Per-layer weight conversion fp32 -> bf16 (with padding) --
__global__ __launch_bounds__(256)
void conv_layer_kernel(const float* __restrict__ wq, const float* __restrict__ wk,
                       const float* __restrict__ wv, const float* __restrict__ wo,
                       const float* __restrict__ w1, const float* __restrict__ w2,
                       const float* __restrict__ w3,
                       ushort_t* __restrict__ wqb, ushort_t* __restrict__ wkb,
                       ushort_t* __restrict__ wvb, ushort_t* __restrict__ wob,
                       ushort_t* __restrict__ w1p, ushort_t* __restrict__ w3p,
                       ushort_t* __restrict__ w2p)
{
    int idx = blockIdx.x * 256 + threadIdx.x;
    if (idx < 4 * QSZ) {
        const int m = idx / QSZ, i = idx - m * QSZ;
        const float* s = (m == 0) ? wq : (m == 1) ? wk : (m == 2) ? wv : wo;
        ushort_t*   d = (m == 0) ? wqb : (m == 1) ? wkb : (m == 2) ? wvb : wob;
        d[i] = f2bf(s[i]);
        return;
    }
    idx -= 4 * QSZ;
    if (idx < PSZ) {   // w1 padded: [2048][768], rows >= 2042 zero
        const int n = idx / DIMC, kk = idx - n * DIMC;
        w1p[idx] = (n < HIDV) ? f2bf(w1[(size_t)n * DIMC + kk]) : (ushort_t)0;
        return;
    }
    idx -= PSZ;
    if (idx < PSZ) {
        const int n = idx / DIMC, kk = idx - n * DIMC;
        w3p[idx] = (n < HIDV) ? f2bf(w3[(size_t)n * DIMC + kk]) : (ushort_t)0;
        return;
    }
    idx -= PSZ;
    if (idx < PSZ) {   // w2 padded: [768][2048], cols >= 2042 zero
        const int n = idx >> 11, kk = idx & 2047;
        w2p[idx] = (kk < HIDV) ? f2bf(w2[(size_t)n * HIDV + kk]) : (ushort_t)0;
        return;
    }
}

// ---------------- out_w conversion fp32 -> bf16 ----------------------------
__global__ __launch_bounds__(256)
void conv_outw_kernel(const float* __restrict__ src, ushort_t* __restrict__ dst)
{
    const size_t idx = (size_t)(blockIdx.x * 256 + threadIdx.x);
    float4 a = *(const float4*)(src + idx * 4);
    *(ushort4*)(dst + idx * 4) = make_ushort4(f2bf(a.x), f2bf(a.y), f2bf(a.z), f2bf(a.w));
}

extern "C" void kernel_launch(void* const* d_in, const int* in_sizes, int n_in,
                              void* d_out, int out_size, void* d_ws, size_t ws_size,
                              hipStream_t stream)
{
    const int*   tok  = (const int*)d_in[0];
    const float* emb  = (const float*)d_in[1];
    const float* wq   = (const float*)d_in[2];
    const float* wk   = (const float*)d_in[3];
    const float* wv   = (const float*)d_in[4];
    const float* wo   = (const float*)d_in[5];
    const float* w1   = (const float*)d_in[6];
    const float* w2   = (const float*)d_in[7];
    const float* w3   = (const float*)d_in[8];
    const float* anw  = (const float*)d_in[9];
    const float* fnw  = (const float*)d_in[10];
    const float* nw   = (const float*)d_in[11];
    const float* outw = (const float*)d_in[12];
    float* out = (float*)d_out;
    (void)in_sizes; (void)n_in; (void)out_size; (void)ws_size;

    char* p = (char*)d_ws;
    auto alloc = [&](size_t bytes) { char* r = p; p += (bytes + 255) & ~(size_t)255; return r; };
    float*    H   = (float*)   alloc((size_t)SEQL * DIMC * 4);
    ushort_t* XN  = (ushort_t*)alloc((size_t)SEQL * DIMC * 2);
    ushort_t* YN  = (ushort_t*)alloc((size_t)SEQL * DIMC * 2);
    ushort_t* WQB = (ushort_t*)alloc((size_t)QSZ * 2);
    ushort_t* WKB = (ushort_t*)alloc((size_t)QSZ * 2);
    ushort_t* WVB = (ushort_t*)alloc((size_t)QSZ * 2);
    ushort_t* WOB = (ushort_t*)alloc((size_t)QSZ * 2);
    ushort_t* W1P = (ushort_t*)alloc((size_t)PSZ * 2);
    ushort_t* W3P = (ushort_t*)alloc((size_t)PSZ * 2);
    ushort_t* W2P = (ushort_t*)alloc((size_t)PSZ * 2);
    // region below is reused late as bf16 out_w (54.5 MB >= 49.15 MB)
    ushort_t* QB  = (ushort_t*)alloc((size_t)SEQL * DIMC * 2);
    ushort_t* KB  = (ushort_t*)alloc((size_t)SEQL * DIMC * 2);
    ushort_t* VTG = (ushort_t*)alloc((size_t)SEQL * DIMC * 2);  // V^T [DIMC][SEQL]
    ushort_t* AO  = (ushort_t*)alloc((size_t)SEQL * DIMC * 2);
    float*    Y1  = (float*)   alloc((size_t)SEQL * HIDP * 4);
    float*    Y3  = (float*)   alloc((size_t)SEQL * HIDP * 4);
    ushort_t* HS  = (ushort_t*)alloc((size_t)SEQL * HIDP * 2);
    ushort_t* OUTWB = QB;  // aliased, used only after last layer

    embed_kernel<<<1536, 256, 0, stream>>>(tok, emb, H);

    for (int l = 0; l < 4; ++l) {
        conv_layer_kernel<<<27648, 256, 0, stream>>>(
            wq + (size_t)l * QSZ, wk + (size_t)l * QSZ, wv + (size_t)l * QSZ, wo + (size_t)l * QSZ,
            w1 + (size_t)l * W2SRC, w2 + (size_t)l * W2SRC, w3 + (size_t)l * W2SRC,
            WQB, WKB, WVB, WOB, W1P, W3P, W2P);

        rmsnorm_kernel<<<512, 256, 0, stream>>>(H, anw + (size_t)l * DIMC, XN);

        // Q,K projections (bf16 out): M=2048 N=768 K=768, 64x64 tiles
        gemm_kernel<2,2,2,2,1><<<dim3(32,12), 256, 0, stream>>>(XN, DIMC, WQB, DIMC, QB, DIMC, DIMC);
        gemm_kernel<2,2,2,2,1><<<dim3(32,12), 256, 0, stream>>>(XN, DIMC, WKB, DIMC, KB, DIMC, DIMC);
        // V^T projection (swapped operands): C[d][s] = sum_k Wv[d][k] X[s][k]
        gemm_kernel<2,2,2,2,1><<<dim3(12,32), 256, 0, stream>>>(WVB, DIMC, XN, DIMC, VTG, SEQL, DIMC);

        rope_kernel<<<3072, 256, 0, stream>>>(QB);
        rope_kernel<<<3072, 256, 0, stream>>>(KB);

        attn_mfma_kernel<<<dim3(32, NHEAD), 256, 0, stream>>>(QB, KB, VTG, AO);

        // o @ wo^T, accumulate into H (residual)
        gemm_kernel<2,2,2,2,2><<<dim3(32,12), 256, 0, stream>>>(AO, DIMC, WOB, DIMC, H, DIMC, DIMC);

        rmsnorm_kernel<<<512, 256, 0, stream>>>(H, fnw + (size_t)l * DIMC, YN);

        // FFN up: M=2048 N=2048(pad) K=768, 128x128 tiles
        gemm_kernel<4,4,2,2,0><<<dim3(16,16), 256, 0, stream>>>(YN, DIMC, W1P, DIMC, Y1, HIDP, DIMC);
        gemm_kernel<4,4,2,2,0><<<dim3(16,16), 256, 0, stream>>>(YN, DIMC, W3P, DIMC, Y3, HIDP, DIMC);

        silu_mul_kernel<<<4096, 256, 0, stream>>>(Y1, Y3, HS);

        // FFN down: M=2048 N=768 K=2048(pad), accumulate into H
        gemm_kernel<2,2,2,2,2><<<dim3(32,12), 256, 0, stream>>>(HS, HIDP, W2P, HIDP, H, DIMC, HIDP);
    }

    rmsnorm_kernel<<<512, 256, 0, stream>>>(H, nw, XN);
    conv_outw_kernel<<<24000, 256, 0, stream>>>(outw, OUTWB);
    // logits: M=2048 N=32000 K=768, 128x128 tiles, f32 out
    gemm_kernel<4,4,2,2,0><<<dim3(16,250), 256, 0, stream>>>(XN, DIMC, OUTWB, DIMC, out, NVOCAB, DIMC);
}